// Round 8
// baseline (353.122 us; speedup 1.0000x reference)
//
#include <hip/hip_runtime.h>
#include <hip/hip_fp16.h>
#include <math.h>

#define EMBED   128
#define NHEADS  8
#define NPOINTS 4
#define HD      16
#define HSP     51
#define WSP     102
#define NPIX    (HSP * WSP)   // 5202
#define NQ      10000
#define NLVL    50
#define TAU     2.0e-4f       // argmax ambiguity threshold (f16 logit err ~1e-5)
#define ROWB    (WSP * HD * 2)   // 3264 bytes per value-grid row per head

typedef _Float16 h2raw __attribute__((ext_vector_type(2)));

__device__ __forceinline__ float fdot2f(__half2 a, __half2 b, float c) {
#if __has_builtin(__builtin_amdgcn_fdot2)
    union { __half2 h; h2raw r; } ua, ub;
    ua.h = a; ub.h = b;
    return __builtin_amdgcn_fdot2(ua.r, ub.r, c, false);
#else
    const float2 fa = __half22float2(a), fb = __half22float2(b);
    return fmaf(fa.y, fb.y, fmaf(fa.x, fb.x, c));
#endif
}

union PkU { uint4 u; __half2 h[4]; };
union W2H { unsigned u; __half2 h; };

// ---------------------------------------------------------------------------
// u = W_out @ W_proj (128 floats) + zero the fixup counter.
// ---------------------------------------------------------------------------
__global__ __launch_bounds__(128) void k_uvec(const float* __restrict__ Wout,
                                              const float* __restrict__ Wproj,
                                              float* __restrict__ u,
                                              int* __restrict__ cnt) {
    const int c = threadIdx.x;
    if (c == 0) *cnt = 0;
    float acc = 0.f;
#pragma unroll 8
    for (int d = 0; d < EMBED; ++d)
        acc = fmaf(Wout[(size_t)c * EMBED + d], Wproj[d], acc);
    u[c] = acc;
}

// ---------------------------------------------------------------------------
// Fused prep kernel (unchanged from R7).
// ---------------------------------------------------------------------------
#define NPB_A ((NPIX + 1) / 2)   // 2601
#define NPB_B (NQ / 2)           // 5000

__global__ __launch_bounds__(256) void k_prep(
    const float* __restrict__ value,
    const float* __restrict__ Wv,
    const float* __restrict__ bv,
    const float* __restrict__ query,
    const float* __restrict__ Woff,
    const float* __restrict__ boff,
    const float* __restrict__ Wattn,
    const float* __restrict__ battn,
    const float* __restrict__ uvec,
    __half* __restrict__ vh,        // (8, NPIX, 16) fp16
    float* __restrict__ gfield,     // (8, NPIX) f32
    float* __restrict__ off_out,
    float* __restrict__ aw_out) {
    const int b = blockIdx.x;
    const int t = threadIdx.x;
    const int unit = t >> 7;
    const int tt = t & 127;

    if (b < NPB_A) {
        __shared__ float vrow[2][EMBED];
        __shared__ float gprod[2][EMBED];
        const int pix = b * 2 + unit;
        vrow[unit][tt] = value[(size_t)pix * EMBED + tt];
        __syncthreads();
        float acc = bv[tt];
        const float* vr = vrow[unit];
#pragma unroll 8
        for (int k = 0; k < EMBED; ++k)
            acc = fmaf(vr[k], Wv[(size_t)k * EMBED + tt], acc);
        const int h = tt >> 4, c = tt & 15;
        vh[((size_t)h * NPIX + pix) * HD + c] = __float2half(acc);
        gprod[unit][tt] = acc * uvec[tt];
        __syncthreads();
        if (t < 16) {
            const int u2 = t >> 3, h2 = t & 7;
            float s = 0.f;
#pragma unroll
            for (int c2 = 0; c2 < HD; ++c2)
                s += gprod[u2][h2 * HD + c2];
            gfield[(size_t)h2 * NPIX + b * 2 + u2] = s;
        }
    } else {
        const int q = (b - NPB_A) * 2 + unit;
        __shared__ float qrow[2][EMBED];
        __shared__ float attn[2][32];
        qrow[unit][tt] = query[(size_t)q * EMBED + tt];
        __syncthreads();
        const float* qr = qrow[unit];
        if (tt < 64) {
            float acc = boff[tt];
#pragma unroll 8
            for (int k = 0; k < EMBED; ++k)
                acc = fmaf(qr[k], Woff[(size_t)k * 64 + tt], acc);
            off_out[(size_t)q * 64 + tt] = acc;
        } else if (tt < 96) {
            const int j = tt - 64;
            float acc = battn[j];
#pragma unroll 8
            for (int k = 0; k < EMBED; ++k)
                acc = fmaf(qr[k], Wattn[(size_t)k * 32 + j], acc);
            attn[unit][j] = acc;
        }
        __syncthreads();
        if (tt < NHEADS) {
            const float a0 = attn[unit][tt * 4 + 0], a1 = attn[unit][tt * 4 + 1];
            const float a2 = attn[unit][tt * 4 + 2], a3 = attn[unit][tt * 4 + 3];
            const float mx = fmaxf(fmaxf(a0, a1), fmaxf(a2, a3));
            const float e0 = __expf(a0 - mx), e1 = __expf(a1 - mx);
            const float e2 = __expf(a2 - mx), e3 = __expf(a3 - mx);
            const float inv = 1.f / (e0 + e1 + e2 + e3);
            aw_out[(size_t)q * 32 + tt * 4 + 0] = e0 * inv;
            aw_out[(size_t)q * 32 + tt * 4 + 1] = e1 * inv;
            aw_out[(size_t)q * 32 + tt * 4 + 2] = e2 * inv;
            aw_out[(size_t)q * 32 + tt * 4 + 3] = e3 * inv;
        }
    }
}

// ---------------------------------------------------------------------------
// Main kernel v8. 1 query/block, 4 waves (levels l = 4i+w).
// lane = h*8 + yc*4 + xc*2 + p2: each lane owns a full head (16 ch packed as
// 8 half2) at one (x,y) corner for a point-pair {p2*2, p2*2+1}. The 64 lanes
// compute the 64 DISTINCT y-states (8h x 2yc x 4p) with zero duplication; the
// xc-twin's y-state arrives via shfl_xor(2). Sampling/accumulation in packed
// f16 (__hfma2), logit via v_dot2_f32_f16 into f32.
// ---------------------------------------------------------------------------
__global__ __launch_bounds__(256, 4) void k_main(
    const float* __restrict__ query,
    const float* __restrict__ refp,   // (NLVL, NQ, 2)
    const float* __restrict__ voff,   // (NQ, 8, 4, 2)
    const float* __restrict__ vaw,    // (NQ, 8, 4)
    const __half* __restrict__ vh,    // (8, NPIX, 16) fp16
    const float* __restrict__ uvec,   // (128)
    const float* __restrict__ Wout,   // (128, 128)
    const float* __restrict__ bout,   // (128)
    float* __restrict__ out0,         // (NQ, 128)
    float* __restrict__ out1,         // (NQ)
    int* __restrict__ cnt,
    int* __restrict__ list) {
    const int t = threadIdx.x;
    const int w = t >> 6;             // wave 0..3
    const int lane = t & 63;
    const int h  = lane >> 3;
    const int yc = (lane >> 2) & 1;
    const int xc = (lane >> 1) & 1;
    const int p2 = lane & 1;
    const int q = blockIdx.x;

    __shared__ float  s_rpy[NLVL];
    __shared__ uint4  s_pub[3][8][2];
    __shared__ float  s_ms[3], s_m2s[3], s_zs[3];
    __shared__ int    s_bs[3];
    __shared__ float4 s_sv[32];

    if (t < NLVL) s_rpy[t] = refp[((size_t)t * NQ + q) * 2 + 1];

    // this lane's point pair: global points p2*2+0, p2*2+1
    const float4 op = *(const float4*)(voff + (size_t)q * 64 + h * 8 + p2 * 4);
    const float2 awp = *(const float2*)(vaw + (size_t)q * 32 + h * 4 + p2 * 2);
    const float rpx = refp[(size_t)q * 2];

    // u for this head, packed f16
    const float4 uA = *(const float4*)(uvec + h * 16);
    const float4 uB = *(const float4*)(uvec + h * 16 + 4);
    const float4 uC = *(const float4*)(uvec + h * 16 + 8);
    const float4 uD = *(const float4*)(uvec + h * 16 + 12);
    const __half2 uh0 = __floats2half2_rn(uA.x, uA.y);
    const __half2 uh1 = __floats2half2_rn(uA.z, uA.w);
    const __half2 uh2 = __floats2half2_rn(uB.x, uB.y);
    const __half2 uh3 = __floats2half2_rn(uB.z, uB.w);
    const __half2 uh4 = __floats2half2_rn(uC.x, uC.y);
    const __half2 uh5 = __floats2half2_rn(uC.z, uC.w);
    const __half2 uh6 = __floats2half2_rn(uD.x, uD.y);
    const __half2 uh7 = __floats2half2_rn(uD.z, uD.w);

    // level-independent x state for the pair (at this lane's x-corner)
    float wlx[2], oyc[2];
    int vbb[2];
    {
        const float ox[2] = {op.x, op.z};
        const float oy[2] = {op.y, op.w};
        const float aww[2] = {awp.x, awp.y};
#pragma unroll
        for (int j = 0; j < 2; ++j) {
            const float px = fmaf(rpx, (float)WSP, ox[j]) - 0.5f;
            const float fx = floorf(px);
            const float dx = px - fx;
            const int xi = (int)fx + xc;
            const float wx = xc ? dx : (1.f - dx);
            wlx[j] = ((unsigned)xi < (unsigned)WSP) ? aww[j] * wx : 0.f;
            const int xcl = min(max(xi, 0), WSP - 1);
            vbb[j] = (h * NPIX + xcl) * (HD * 2);   // byte offset
            oyc[j] = oy[j] - 0.5f;
        }
    }
    const char* vbase = (const char*)vh;

    __syncthreads();

    const __half2 hzero = __float2half2_rn(0.f);
    __half2 acc0 = hzero, acc1 = hzero, acc2 = hzero, acc3 = hzero;
    __half2 acc4 = hzero, acc5 = hzero, acc6 = hzero, acc7 = hzero;
    float Z = 0.f, m = -1e30f, m2 = -1e30f;
    int best = 0;

#pragma unroll 1
    for (int i = 0; i < 13; ++i) {
        const int l = 4 * i + w;
        if (l >= NLVL) break;         // wave-uniform (w)
        const float rpy = s_rpy[l];
        // y-state for own point (local index = xc)
        const float py = fmaf(rpy, (float)HSP, oyc[xc]);
        const float fy = floorf(py);
        const float dy = py - fy;
        const int yi = (int)fy + yc;
        const float wy = yc ? dy : (1.f - dy);
        const float wv = ((unsigned)yi < (unsigned)HSP) ? wy : 0.f;
        const int row = min(max(yi, 0), HSP - 1);
        // twin exchange: other point's y-state (same yc, other xc computed it)
        const float wvB = __shfl_xor(wv, 2, 64);
        const int  rowB = __shfl_xor(row, 2, 64);

        __half2 s0 = hzero, s1 = hzero, s2 = hzero, s3 = hzero;
        __half2 s4 = hzero, s5 = hzero, s6 = hzero, s7 = hzero;
        // point A (local xc)
        {
            const __half2 wh = __float2half2_rn(wlx[xc] * wv);
            const int off = vbb[xc] + row * ROWB;
            PkU ra, rb;
            ra.u = *(const uint4*)(vbase + off);
            rb.u = *(const uint4*)(vbase + off + 16);
            s0 = __hfma2(wh, ra.h[0], s0); s1 = __hfma2(wh, ra.h[1], s1);
            s2 = __hfma2(wh, ra.h[2], s2); s3 = __hfma2(wh, ra.h[3], s3);
            s4 = __hfma2(wh, rb.h[0], s4); s5 = __hfma2(wh, rb.h[1], s5);
            s6 = __hfma2(wh, rb.h[2], s6); s7 = __hfma2(wh, rb.h[3], s7);
        }
        // point B (local xc^1), using the twin's y-state
        {
            const int xo = xc ^ 1;
            const __half2 wh = __float2half2_rn(wlx[xo] * wvB);
            const int off = vbb[xo] + rowB * ROWB;
            PkU ra, rb;
            ra.u = *(const uint4*)(vbase + off);
            rb.u = *(const uint4*)(vbase + off + 16);
            s0 = __hfma2(wh, ra.h[0], s0); s1 = __hfma2(wh, ra.h[1], s1);
            s2 = __hfma2(wh, ra.h[2], s2); s3 = __hfma2(wh, ra.h[3], s3);
            s4 = __hfma2(wh, rb.h[0], s4); s5 = __hfma2(wh, rb.h[1], s5);
            s6 = __hfma2(wh, rb.h[2], s6); s7 = __hfma2(wh, rb.h[3], s7);
        }
        // logit: f32 dot via v_dot2_f32_f16, then full 64-lane reduce
        float part = fdot2f(s0, uh0, 0.f);
        part = fdot2f(s1, uh1, part);
        part = fdot2f(s2, uh2, part);
        part = fdot2f(s3, uh3, part);
        part = fdot2f(s4, uh4, part);
        part = fdot2f(s5, uh5, part);
        part = fdot2f(s6, uh6, part);
        part = fdot2f(s7, uh7, part);
#pragma unroll
        for (int d = 1; d < 64; d <<= 1)
            part += __shfl_xor(part, d, 64);
        const float e = __expf(part);
        Z += e;
        const __half2 eh = __float2half2_rn(e);
        acc0 = __hfma2(eh, s0, acc0); acc1 = __hfma2(eh, s1, acc1);
        acc2 = __hfma2(eh, s2, acc2); acc3 = __hfma2(eh, s3, acc3);
        acc4 = __hfma2(eh, s4, acc4); acc5 = __hfma2(eh, s5, acc5);
        acc6 = __hfma2(eh, s6, acc6); acc7 = __hfma2(eh, s7, acc7);
        if (part > m) { m2 = m; m = part; best = l; }
        else          { m2 = fmaxf(m2, part); }
    }

    // merge accumulators across p2(bit0), xc(bit1), yc(bit2)
#pragma unroll
    for (int d = 1; d <= 4; d <<= 1) {
        W2H v;
#define MRG(A) v.h = A; v.u = __shfl_xor((int)v.u, d, 64); A = __hadd2(A, v.h);
        MRG(acc0) MRG(acc1) MRG(acc2) MRG(acc3)
        MRG(acc4) MRG(acc5) MRG(acc6) MRG(acc7)
#undef MRG
    }

    // waves 1..3 publish; wave 0 merges
    if (w > 0) {
        if ((lane & 7) == 0) {
            PkU pa, pb;
            pa.h[0] = acc0; pa.h[1] = acc1; pa.h[2] = acc2; pa.h[3] = acc3;
            pb.h[0] = acc4; pb.h[1] = acc5; pb.h[2] = acc6; pb.h[3] = acc7;
            s_pub[w - 1][h][0] = pa.u;
            s_pub[w - 1][h][1] = pb.u;
        }
        if (lane == 0) {
            s_ms[w - 1] = m; s_m2s[w - 1] = m2;
            s_zs[w - 1] = Z; s_bs[w - 1] = best;
        }
    }
    __syncthreads();

    if (w == 0) {
#pragma unroll
        for (int j = 0; j < 3; ++j) {
            if ((lane & 7) == 0) {
                PkU pa, pb;
                pa.u = s_pub[j][h][0];
                pb.u = s_pub[j][h][1];
                acc0 = __hadd2(acc0, pa.h[0]); acc1 = __hadd2(acc1, pa.h[1]);
                acc2 = __hadd2(acc2, pa.h[2]); acc3 = __hadd2(acc3, pa.h[3]);
                acc4 = __hadd2(acc4, pb.h[0]); acc5 = __hadd2(acc5, pb.h[1]);
                acc6 = __hadd2(acc6, pb.h[2]); acc7 = __hadd2(acc7, pb.h[3]);
            }
            const float mo = s_ms[j], m2o = s_m2s[j], Zo = s_zs[j];
            const int bo = s_bs[j];
            const bool takeOther = (mo > m) || (mo == m && bo < best);
            m2 = fmaxf(fmaxf(m2, m2o), fminf(m, mo));
            best = takeOther ? bo : best;
            m = fmaxf(m, mo);
            Z += Zo;
        }
        const float inv = 1.f / Z;
        if ((lane & 7) == 0) {
            const float2 f0 = __half22float2(acc0);
            const float2 f1 = __half22float2(acc1);
            const float2 f2 = __half22float2(acc2);
            const float2 f3 = __half22float2(acc3);
            const float2 f4 = __half22float2(acc4);
            const float2 f5 = __half22float2(acc5);
            const float2 f6 = __half22float2(acc6);
            const float2 f7 = __half22float2(acc7);
            s_sv[h * 4 + 0] = make_float4(f0.x * inv, f0.y * inv, f1.x * inv, f1.y * inv);
            s_sv[h * 4 + 1] = make_float4(f2.x * inv, f2.y * inv, f3.x * inv, f3.y * inv);
            s_sv[h * 4 + 2] = make_float4(f4.x * inv, f4.y * inv, f5.x * inv, f5.y * inv);
            s_sv[h * 4 + 3] = make_float4(f6.x * inv, f6.y * inv, f7.x * inv, f7.y * inv);
        }
        if (lane == 0) {
            out1[q] = (float)best;
            if (m - m2 < TAU) {
                const int ii = atomicAdd(cnt, 1);
                list[ii] = q;
            }
        }
        // same-wave DS ordering: s_sv writes visible to wave 0's reads below

        // epilogue: out[dp] = sum_c s[c]*Wout[c][dp] + bout[dp] + 2*query[q][dp]
        const int sub = lane & 31;
        const int half = lane >> 5;
        const int dpb = sub * 4;
        float4 r = {0.f, 0.f, 0.f, 0.f};
        if (half == 0) {
            const float4 b4 = *(const float4*)(bout + dpb);
            const float4 q4 = *(const float4*)(query + (size_t)q * EMBED + dpb);
            r.x = fmaf(2.f, q4.x, b4.x);
            r.y = fmaf(2.f, q4.y, b4.y);
            r.z = fmaf(2.f, q4.z, b4.z);
            r.w = fmaf(2.f, q4.w, b4.w);
        }
        const int cg0 = half * 16;
#pragma unroll 4
        for (int cg = cg0; cg < cg0 + 16; ++cg) {
            const float4 s4 = s_sv[cg];
            const float4 w0 = *(const float4*)(Wout + (size_t)(cg * 4 + 0) * EMBED + dpb);
            const float4 w1 = *(const float4*)(Wout + (size_t)(cg * 4 + 1) * EMBED + dpb);
            const float4 w2v = *(const float4*)(Wout + (size_t)(cg * 4 + 2) * EMBED + dpb);
            const float4 w3 = *(const float4*)(Wout + (size_t)(cg * 4 + 3) * EMBED + dpb);
            r.x = fmaf(s4.x, w0.x, r.x); r.y = fmaf(s4.x, w0.y, r.y);
            r.z = fmaf(s4.x, w0.z, r.z); r.w = fmaf(s4.x, w0.w, r.w);
            r.x = fmaf(s4.y, w1.x, r.x); r.y = fmaf(s4.y, w1.y, r.y);
            r.z = fmaf(s4.y, w1.z, r.z); r.w = fmaf(s4.y, w1.w, r.w);
            r.x = fmaf(s4.z, w2v.x, r.x); r.y = fmaf(s4.z, w2v.y, r.y);
            r.z = fmaf(s4.z, w2v.z, r.z); r.w = fmaf(s4.z, w2v.w, r.w);
            r.x = fmaf(s4.w, w3.x, r.x); r.y = fmaf(s4.w, w3.y, r.y);
            r.z = fmaf(s4.w, w3.z, r.z); r.w = fmaf(s4.w, w3.w, r.w);
        }
        {
            const float rx = __shfl_xor(r.x, 32, 64);
            const float ry = __shfl_xor(r.y, 32, 64);
            const float rz = __shfl_xor(r.z, 32, 64);
            const float rw = __shfl_xor(r.w, 32, 64);
            r.x += rx; r.y += ry; r.z += rz; r.w += rw;
        }
        if (half == 0)
            *(float4*)(out0 + (size_t)q * EMBED + dpb) = r;
    }
}

// ---------------------------------------------------------------------------
// Exact-f32 argmax fixup for flagged queries (unchanged from R7).
// ---------------------------------------------------------------------------
__global__ __launch_bounds__(64) void k_fix(
    const float* __restrict__ refp,
    const float* __restrict__ voff,
    const float* __restrict__ vaw,
    const float* __restrict__ gfield,  // (8, NPIX)
    const int* __restrict__ cnt,
    const int* __restrict__ list,
    float* __restrict__ out1) {
    const int n = *cnt;
    const int lane = threadIdx.x;
    for (int idx = blockIdx.x; idx < n; idx += gridDim.x) {
        const int q = list[idx];
        float logit = -1e30f;
        if (lane < NLVL) {
            const float rpx = refp[(size_t)q * 2];
            const float rpy = refp[((size_t)lane * NQ + q) * 2 + 1];
            float accl = 0.f;
            for (int h = 0; h < NHEADS; ++h) {
                const float4 o01 = *(const float4*)(voff + (size_t)q * 64 + h * 8);
                const float4 o23 = *(const float4*)(voff + (size_t)q * 64 + h * 8 + 4);
                const float4 aw4 = *(const float4*)(vaw + (size_t)q * 32 + h * 4);
                const float* gh = gfield + (size_t)h * NPIX;
                const float offx[4] = {o01.x, o01.z, o23.x, o23.z};
                const float offy[4] = {o01.y, o01.w, o23.y, o23.w};
                const float aww[4]  = {aw4.x, aw4.y, aw4.z, aw4.w};
#pragma unroll
                for (int p = 0; p < NPOINTS; ++p) {
                    const float px = fmaf(rpx, (float)WSP, offx[p]) - 0.5f;
                    const float py = fmaf(rpy, (float)HSP, offy[p]) - 0.5f;
                    const float fx = floorf(px), fy = floorf(py);
                    const float dx = px - fx, dy = py - fy;
                    const int x0 = (int)fx, y0 = (int)fy;
                    const float wx0 = ((unsigned)x0 < (unsigned)WSP) ? (1.f - dx) : 0.f;
                    const float wx1 = ((unsigned)(x0 + 1) < (unsigned)WSP) ? dx : 0.f;
                    const float t0 = ((unsigned)y0 < (unsigned)HSP) ? (1.f - dy) : 0.f;
                    const float t1 = ((unsigned)(y0 + 1) < (unsigned)HSP) ? dy : 0.f;
                    const int xc0 = min(max(x0, 0), WSP - 1);
                    const int xc1 = min(max(x0 + 1, 0), WSP - 1);
                    const int rb0 = min(max(y0, 0), HSP - 1) * WSP;
                    const int rb1 = min(max(y0 + 1, 0), HSP - 1) * WSP;
                    const float g00 = gh[rb0 + xc0];
                    const float g01 = gh[rb0 + xc1];
                    const float g10 = gh[rb1 + xc0];
                    const float g11 = gh[rb1 + xc1];
                    const float bil = wx0 * t0 * g00 + wx1 * t0 * g01
                                    + wx0 * t1 * g10 + wx1 * t1 * g11;
                    accl = fmaf(aww[p], bil, accl);
                }
            }
            logit = accl;
        }
        float v = logit;
        int b = lane;
#pragma unroll
        for (int d = 1; d < 64; d <<= 1) {
            const float vo = __shfl_xor(v, d, 64);
            const int bo = __shfl_xor(b, d, 64);
            if ((vo > v) || (vo == v && bo < b)) { v = vo; b = bo; }
        }
        if (lane == 0) out1[q] = (float)b;
    }
}

// ---------------------------------------------------------------------------
extern "C" void kernel_launch(void* const* d_in, const int* in_sizes, int n_in,
                              void* d_out, int out_size, void* d_ws, size_t ws_size,
                              hipStream_t stream) {
    const float* query = (const float*)d_in[0];
    const float* value = (const float*)d_in[1];
    const float* refp  = (const float*)d_in[2];
    const float* Woff  = (const float*)d_in[3];
    const float* boff  = (const float*)d_in[4];
    const float* Wattn = (const float*)d_in[5];
    const float* battn = (const float*)d_in[6];
    const float* Wval  = (const float*)d_in[7];
    const float* bval  = (const float*)d_in[8];
    const float* Wout  = (const float*)d_in[9];
    const float* bout  = (const float*)d_in[10];
    const float* Wproj = (const float*)d_in[11];
    // d_in[12] = b_proj: level-constant -> cancels in softmax/argmax, unused.

    float* ws = (float*)d_ws;
    __half* ws_vh = (__half*)ws;                          // 8*5202*16 halves
    float* ws_g   = ws + ((size_t)NHEADS * NPIX * HD + 1) / 2;  // 8*5202 f
    float* ws_off = ws_g + (size_t)NHEADS * NPIX;         // NQ*64
    float* ws_aw  = ws_off + (size_t)NQ * 64;             // NQ*32
    float* ws_u   = ws_aw + (size_t)NQ * 32;              // 128
    int*   ws_cnt = (int*)(ws_u + 128);                   // 1
    int*   ws_list = ws_cnt + 1;                          // NQ

    float* out0 = (float*)d_out;
    float* out1 = out0 + (size_t)NQ * EMBED;

    hipLaunchKernelGGL(k_uvec, dim3(1), dim3(128), 0, stream,
                       Wout, Wproj, ws_u, ws_cnt);
    hipLaunchKernelGGL(k_prep, dim3(NPB_A + NPB_B), dim3(256), 0, stream,
                       value, Wval, bval, query, Woff, boff, Wattn, battn,
                       ws_u, ws_vh, ws_g, ws_off, ws_aw);
    hipLaunchKernelGGL(k_main, dim3(NQ), dim3(256), 0, stream,
                       query, refp, ws_off, ws_aw, ws_vh, ws_u, Wout, bout,
                       out0, out1, ws_cnt, ws_list);
    hipLaunchKernelGGL(k_fix, dim3(256), dim3(64), 0, stream,
                       refp, ws_off, ws_aw, ws_g, ws_cnt, ws_list, out1);
}

// Round 9
// 313.919 us; speedup vs baseline: 1.1249x; 1.1249x over previous
//
#include <hip/hip_runtime.h>
#include <hip/hip_fp16.h>
#include <math.h>

#define EMBED   128
#define NHEADS  8
#define NPOINTS 4
#define HD      16
#define HSP     51
#define WSP     102
#define NPIX    (HSP * WSP)   // 5202
#define NQ      10000
#define NLVL    50
#define TAU     2.0e-4f       // argmax ambiguity threshold (f16 logit err ~1e-5)
#define ROWB    (WSP * HD * 2)   // 3264 bytes per value-grid row per head

typedef _Float16 h2raw __attribute__((ext_vector_type(2)));

__device__ __forceinline__ float fdot2f(__half2 a, __half2 b, float c) {
#if __has_builtin(__builtin_amdgcn_fdot2)
    union { __half2 h; h2raw r; } ua, ub;
    ua.h = a; ub.h = b;
    return __builtin_amdgcn_fdot2(ua.r, ub.r, c, false);
#else
    const float2 fa = __half22float2(a), fb = __half22float2(b);
    return fmaf(fa.y, fb.y, fmaf(fa.x, fb.x, c));
#endif
}

union PkU { uint4 u; __half2 h[4]; };
union W2H { unsigned u; __half2 h; };

// ---------------------------------------------------------------------------
// u = W_out @ W_proj (128 floats) + zero the fixup counter.
// ---------------------------------------------------------------------------
__global__ __launch_bounds__(128) void k_uvec(const float* __restrict__ Wout,
                                              const float* __restrict__ Wproj,
                                              float* __restrict__ u,
                                              int* __restrict__ cnt) {
    const int c = threadIdx.x;
    if (c == 0) *cnt = 0;
    float acc = 0.f;
#pragma unroll 8
    for (int d = 0; d < EMBED; ++d)
        acc = fmaf(Wout[(size_t)c * EMBED + d], Wproj[d], acc);
    u[c] = acc;
}

// ---------------------------------------------------------------------------
// k_prep v9: batched GEMM-style prep. 256 threads/block.
//   blocks [0, NVB)        : 16 pixels/block value projection + fp16 + gfield
//   blocks [NVB, NVB+NQB)  : 16 queries/block offsets + attention softmax
// Replaces the 7600-block latency-bound version (~85 us -> ~12 us predicted).
// ---------------------------------------------------------------------------
#define VPB 16
#define NVB ((NPIX + VPB - 1) / VPB)   // 326
#define QPB 16
#define NQB (NQ / QPB)                  // 625

__global__ __launch_bounds__(256) void k_prep(
    const float* __restrict__ value,
    const float* __restrict__ Wv,
    const float* __restrict__ bv,
    const float* __restrict__ query,
    const float* __restrict__ Woff,
    const float* __restrict__ boff,
    const float* __restrict__ Wattn,
    const float* __restrict__ battn,
    const float* __restrict__ uvec,
    __half* __restrict__ vh,        // (8, NPIX, 16) fp16
    float* __restrict__ gfield,     // (8, NPIX) f32
    float* __restrict__ off_out,
    float* __restrict__ aw_out) {
    const int b = blockIdx.x;
    const int t = threadIdx.x;

    if (b < NVB) {  // ---- value projection ----
        __shared__ float4 vrow4[VPB][32];   // [pix_local][k4] = 8 KB
        const int pix0 = b * VPB;
#pragma unroll
        for (int j = 0; j < 2; ++j) {
            const int idx = t + 256 * j;
            const int pl = idx >> 5, c4 = idx & 31;
            const int pg = pix0 + pl;
            float4 v = make_float4(0.f, 0.f, 0.f, 0.f);
            if (pg < NPIX) v = *(const float4*)(value + (size_t)pg * EMBED + c4 * 4);
            vrow4[pl][c4] = v;
        }
        __syncthreads();
        const int c = t & 127;
        const int g = t >> 7;               // pixel half: g*8 .. g*8+7
        float acc[8];
        const float bvc = bv[c];
#pragma unroll
        for (int j = 0; j < 8; ++j) acc[j] = bvc;
#pragma unroll 4
        for (int k4 = 0; k4 < 32; ++k4) {
            const float w0 = Wv[(size_t)(k4 * 4 + 0) * EMBED + c];
            const float w1 = Wv[(size_t)(k4 * 4 + 1) * EMBED + c];
            const float w2 = Wv[(size_t)(k4 * 4 + 2) * EMBED + c];
            const float w3 = Wv[(size_t)(k4 * 4 + 3) * EMBED + c];
#pragma unroll
            for (int j = 0; j < 8; ++j) {
                const float4 v = vrow4[g * 8 + j][k4];
                acc[j] = fmaf(v.x, w0, acc[j]);
                acc[j] = fmaf(v.y, w1, acc[j]);
                acc[j] = fmaf(v.z, w2, acc[j]);
                acc[j] = fmaf(v.w, w3, acc[j]);
            }
        }
        const float uc = uvec[c];
        const int h = c >> 4, cc = c & 15;
        __syncthreads();                    // done reading vrow4; reuse as gtile
        float* gt = (float*)vrow4;          // [pix_local][128]
#pragma unroll
        for (int j = 0; j < 8; ++j) {
            const int pl = g * 8 + j;
            const int pg = pix0 + pl;
            if (pg < NPIX)
                vh[((size_t)h * NPIX + pg) * HD + cc] = __float2half(acc[j]);
            gt[pl * EMBED + c] = acc[j] * uc;
        }
        __syncthreads();
        if (t < 128) {
            const int pl = t >> 3, hh = t & 7;
            const int pg = pix0 + pl;
            float s = 0.f;
#pragma unroll
            for (int i2 = 0; i2 < 16; ++i2)
                s += gt[pl * EMBED + hh * 16 + i2];
            if (pg < NPIX) gfield[(size_t)hh * NPIX + pg] = s;
        }
    } else {  // ---- offsets + attention ----
        const int q0 = (b - NVB) * QPB;
        __shared__ float4 qrow4[QPB][32];   // 8 KB
        __shared__ float sattn[QPB][32];    // 2 KB
#pragma unroll
        for (int j = 0; j < 2; ++j) {
            const int idx = t + 256 * j;
            const int ql = idx >> 5, c4 = idx & 31;
            qrow4[ql][c4] = *(const float4*)(query + (size_t)(q0 + ql) * EMBED + c4 * 4);
        }
        __syncthreads();
        // phase 1: offsets (64 outs), 4 queries per thread
        {
            const int o = t & 63, qg = t >> 6;
            float acc[4];
            const float b0 = boff[o];
#pragma unroll
            for (int j = 0; j < 4; ++j) acc[j] = b0;
#pragma unroll 4
            for (int k4 = 0; k4 < 32; ++k4) {
                const float w0 = Woff[(size_t)(k4 * 4 + 0) * 64 + o];
                const float w1 = Woff[(size_t)(k4 * 4 + 1) * 64 + o];
                const float w2 = Woff[(size_t)(k4 * 4 + 2) * 64 + o];
                const float w3 = Woff[(size_t)(k4 * 4 + 3) * 64 + o];
#pragma unroll
                for (int j = 0; j < 4; ++j) {
                    const float4 v = qrow4[qg * 4 + j][k4];
                    acc[j] = fmaf(v.x, w0, acc[j]);
                    acc[j] = fmaf(v.y, w1, acc[j]);
                    acc[j] = fmaf(v.z, w2, acc[j]);
                    acc[j] = fmaf(v.w, w3, acc[j]);
                }
            }
#pragma unroll
            for (int j = 0; j < 4; ++j)
                off_out[(size_t)(q0 + qg * 4 + j) * 64 + o] = acc[j];
        }
        // phase 2: attn logits (32 outs), 2 queries per thread
        {
            const int a = t & 31, qg = t >> 5;
            float acc[2];
            const float b0 = battn[a];
            acc[0] = b0; acc[1] = b0;
#pragma unroll 4
            for (int k4 = 0; k4 < 32; ++k4) {
                const float w0 = Wattn[(size_t)(k4 * 4 + 0) * 32 + a];
                const float w1 = Wattn[(size_t)(k4 * 4 + 1) * 32 + a];
                const float w2 = Wattn[(size_t)(k4 * 4 + 2) * 32 + a];
                const float w3 = Wattn[(size_t)(k4 * 4 + 3) * 32 + a];
#pragma unroll
                for (int j = 0; j < 2; ++j) {
                    const float4 v = qrow4[qg * 2 + j][k4];
                    acc[j] = fmaf(v.x, w0, acc[j]);
                    acc[j] = fmaf(v.y, w1, acc[j]);
                    acc[j] = fmaf(v.z, w2, acc[j]);
                    acc[j] = fmaf(v.w, w3, acc[j]);
                }
            }
            sattn[qg * 2 + 0][a] = acc[0];
            sattn[qg * 2 + 1][a] = acc[1];
        }
        __syncthreads();
        if (t < 128) {
            const int ql = t >> 3, hh = t & 7;
            const float a0 = sattn[ql][hh * 4 + 0], a1 = sattn[ql][hh * 4 + 1];
            const float a2 = sattn[ql][hh * 4 + 2], a3 = sattn[ql][hh * 4 + 3];
            const float mx = fmaxf(fmaxf(a0, a1), fmaxf(a2, a3));
            const float e0 = __expf(a0 - mx), e1 = __expf(a1 - mx);
            const float e2 = __expf(a2 - mx), e3 = __expf(a3 - mx);
            const float inv = 1.f / (e0 + e1 + e2 + e3);
            float* dst = aw_out + (size_t)(q0 + ql) * 32 + hh * 4;
            dst[0] = e0 * inv; dst[1] = e1 * inv;
            dst[2] = e2 * inv; dst[3] = e3 * inv;
        }
    }
}

// ---------------------------------------------------------------------------
// Main kernel v9. 1 query/block, 4 waves (levels l = 4i+w).
// lane = h*8 + yc*4 + xc*2 + ph: each lane owns ONE (x,y) corner of a point
// pair {2ph, 2ph+1} for head h, loading the full 16-ch record (2x16B) with
// self-computed addresses (no shfl in the load path — R8's mistake). Packed
// f16 sampling (__hfma2), fdot2 logits. ~70 VALU + 4 vmem per level.
// ---------------------------------------------------------------------------
__global__ __launch_bounds__(256, 4) void k_main(
    const float* __restrict__ query,
    const float* __restrict__ refp,   // (NLVL, NQ, 2)
    const float* __restrict__ voff,   // (NQ, 8, 4, 2)
    const float* __restrict__ vaw,    // (NQ, 8, 4)
    const __half* __restrict__ vh,    // (8, NPIX, 16) fp16
    const float* __restrict__ uvec,   // (128)
    const float* __restrict__ Wout,   // (128, 128)
    const float* __restrict__ bout,   // (128)
    float* __restrict__ out0,         // (NQ, 128)
    float* __restrict__ out1,         // (NQ)
    int* __restrict__ cnt,
    int* __restrict__ list) {
    const int t = threadIdx.x;
    const int w = t >> 6;             // wave 0..3
    const int lane = t & 63;
    const int h  = lane >> 3;
    const int yc = (lane >> 2) & 1;
    const int xc = (lane >> 1) & 1;
    const int ph = lane & 1;          // point pair: {2ph, 2ph+1}
    const int q = blockIdx.x;

    __shared__ float  s_rpy[NLVL];
    __shared__ uint4  s_pub[3][8][2];
    __shared__ float  s_ms[3], s_m2s[3], s_zs[3];
    __shared__ int    s_bs[3];
    __shared__ float4 s_sv[32];

    if (t < NLVL) s_rpy[t] = refp[((size_t)t * NQ + q) * 2 + 1];

    const float4 op = *(const float4*)(voff + (size_t)q * 64 + h * 8 + ph * 4);
    const float2 awp = *(const float2*)(vaw + (size_t)q * 32 + h * 4 + ph * 2);
    const float rpx = refp[(size_t)q * 2];

    // u for this head, packed f16
    const float4 uA = *(const float4*)(uvec + h * 16);
    const float4 uB = *(const float4*)(uvec + h * 16 + 4);
    const float4 uC = *(const float4*)(uvec + h * 16 + 8);
    const float4 uD = *(const float4*)(uvec + h * 16 + 12);
    const __half2 uh0 = __floats2half2_rn(uA.x, uA.y);
    const __half2 uh1 = __floats2half2_rn(uA.z, uA.w);
    const __half2 uh2 = __floats2half2_rn(uB.x, uB.y);
    const __half2 uh3 = __floats2half2_rn(uB.z, uB.w);
    const __half2 uh4 = __floats2half2_rn(uC.x, uC.y);
    const __half2 uh5 = __floats2half2_rn(uC.z, uC.w);
    const __half2 uh6 = __floats2half2_rn(uD.x, uD.y);
    const __half2 uh7 = __floats2half2_rn(uD.z, uD.w);

    // level-independent x state for the 2 points (at this lane's x-corner)
    float wlx0, wlx1, oyc0, oyc1;
    int vbb0, vbb1;
    {
        const float px0 = fmaf(rpx, (float)WSP, op.x) - 0.5f;
        const float fx0 = floorf(px0);
        const float dx0 = px0 - fx0;
        const int xi0 = (int)fx0 + xc;
        const float wx0 = xc ? dx0 : (1.f - dx0);
        wlx0 = ((unsigned)xi0 < (unsigned)WSP) ? awp.x * wx0 : 0.f;
        vbb0 = (h * NPIX + min(max(xi0, 0), WSP - 1)) * (HD * 2);
        oyc0 = op.y - 0.5f;

        const float px1 = fmaf(rpx, (float)WSP, op.z) - 0.5f;
        const float fx1 = floorf(px1);
        const float dx1 = px1 - fx1;
        const int xi1 = (int)fx1 + xc;
        const float wx1 = xc ? dx1 : (1.f - dx1);
        wlx1 = ((unsigned)xi1 < (unsigned)WSP) ? awp.y * wx1 : 0.f;
        vbb1 = (h * NPIX + min(max(xi1, 0), WSP - 1)) * (HD * 2);
        oyc1 = op.w - 0.5f;
    }
    const char* vbase = (const char*)vh;

    __syncthreads();

    const __half2 hzero = __float2half2_rn(0.f);
    __half2 acc0 = hzero, acc1 = hzero, acc2 = hzero, acc3 = hzero;
    __half2 acc4 = hzero, acc5 = hzero, acc6 = hzero, acc7 = hzero;
    float Z = 0.f, m = -1e30f, m2 = -1e30f;
    int best = 0;

#pragma unroll 1
    for (int i = 0; i < 13; ++i) {
        const int l = 4 * i + w;
        if (l >= NLVL) break;         // wave-uniform (w)
        const float rpy = s_rpy[l];

        // y-state for the lane's 2 points (self-contained, no shfl)
        const float py0 = fmaf(rpy, (float)HSP, oyc0);
        const float fy0 = floorf(py0);
        const float dy0 = py0 - fy0;
        const int yi0 = (int)fy0 + yc;
        const float wy0 = yc ? dy0 : (1.f - dy0);
        const float wv0 = ((unsigned)yi0 < (unsigned)HSP) ? wy0 : 0.f;
        const int off0 = vbb0 + min(max(yi0, 0), HSP - 1) * ROWB;

        const float py1 = fmaf(rpy, (float)HSP, oyc1);
        const float fy1 = floorf(py1);
        const float dy1 = py1 - fy1;
        const int yi1 = (int)fy1 + yc;
        const float wy1 = yc ? dy1 : (1.f - dy1);
        const float wv1 = ((unsigned)yi1 < (unsigned)HSP) ? wy1 : 0.f;
        const int off1 = vbb1 + min(max(yi1, 0), HSP - 1) * ROWB;

        PkU ra0, rb0, ra1, rb1;
        ra0.u = *(const uint4*)(vbase + off0);
        rb0.u = *(const uint4*)(vbase + off0 + 16);
        ra1.u = *(const uint4*)(vbase + off1);
        rb1.u = *(const uint4*)(vbase + off1 + 16);

        const __half2 wh0 = __float2half2_rn(wlx0 * wv0);
        const __half2 wh1 = __float2half2_rn(wlx1 * wv1);

        __half2 s0, s1, s2, s3, s4, s5, s6, s7;
        s0 = __hmul2(wh0, ra0.h[0]); s1 = __hmul2(wh0, ra0.h[1]);
        s2 = __hmul2(wh0, ra0.h[2]); s3 = __hmul2(wh0, ra0.h[3]);
        s4 = __hmul2(wh0, rb0.h[0]); s5 = __hmul2(wh0, rb0.h[1]);
        s6 = __hmul2(wh0, rb0.h[2]); s7 = __hmul2(wh0, rb0.h[3]);
        s0 = __hfma2(wh1, ra1.h[0], s0); s1 = __hfma2(wh1, ra1.h[1], s1);
        s2 = __hfma2(wh1, ra1.h[2], s2); s3 = __hfma2(wh1, ra1.h[3], s3);
        s4 = __hfma2(wh1, rb1.h[0], s4); s5 = __hfma2(wh1, rb1.h[1], s5);
        s6 = __hfma2(wh1, rb1.h[2], s6); s7 = __hfma2(wh1, rb1.h[3], s7);

        // logit: f32 dot via v_dot2_f32_f16, then full 64-lane reduce
        float pa = fdot2f(s0, uh0, 0.f);
        pa = fdot2f(s1, uh1, pa);
        pa = fdot2f(s2, uh2, pa);
        pa = fdot2f(s3, uh3, pa);
        float pb = fdot2f(s4, uh4, 0.f);
        pb = fdot2f(s5, uh5, pb);
        pb = fdot2f(s6, uh6, pb);
        pb = fdot2f(s7, uh7, pb);
        float part = pa + pb;
#pragma unroll
        for (int d = 1; d < 64; d <<= 1)
            part += __shfl_xor(part, d, 64);
        const float e = __expf(part);
        Z += e;
        const __half2 eh = __float2half2_rn(e);
        acc0 = __hfma2(eh, s0, acc0); acc1 = __hfma2(eh, s1, acc1);
        acc2 = __hfma2(eh, s2, acc2); acc3 = __hfma2(eh, s3, acc3);
        acc4 = __hfma2(eh, s4, acc4); acc5 = __hfma2(eh, s5, acc5);
        acc6 = __hfma2(eh, s6, acc6); acc7 = __hfma2(eh, s7, acc7);
        if (part > m) { m2 = m; m = part; best = l; }
        else          { m2 = fmaxf(m2, part); }
    }

    // merge accumulators across ph(bit0), xc(bit1), yc(bit2)
#pragma unroll
    for (int d = 1; d <= 4; d <<= 1) {
        W2H v;
#define MRG(A) v.h = A; v.u = __shfl_xor((int)v.u, d, 64); A = __hadd2(A, v.h);
        MRG(acc0) MRG(acc1) MRG(acc2) MRG(acc3)
        MRG(acc4) MRG(acc5) MRG(acc6) MRG(acc7)
#undef MRG
    }

    // waves 1..3 publish; wave 0 merges
    if (w > 0) {
        if ((lane & 7) == 0) {
            PkU pa, pb;
            pa.h[0] = acc0; pa.h[1] = acc1; pa.h[2] = acc2; pa.h[3] = acc3;
            pb.h[0] = acc4; pb.h[1] = acc5; pb.h[2] = acc6; pb.h[3] = acc7;
            s_pub[w - 1][h][0] = pa.u;
            s_pub[w - 1][h][1] = pb.u;
        }
        if (lane == 0) {
            s_ms[w - 1] = m; s_m2s[w - 1] = m2;
            s_zs[w - 1] = Z; s_bs[w - 1] = best;
        }
    }
    __syncthreads();

    if (w == 0) {
#pragma unroll
        for (int j = 0; j < 3; ++j) {
            if ((lane & 7) == 0) {
                PkU pa, pb;
                pa.u = s_pub[j][h][0];
                pb.u = s_pub[j][h][1];
                acc0 = __hadd2(acc0, pa.h[0]); acc1 = __hadd2(acc1, pa.h[1]);
                acc2 = __hadd2(acc2, pa.h[2]); acc3 = __hadd2(acc3, pa.h[3]);
                acc4 = __hadd2(acc4, pb.h[0]); acc5 = __hadd2(acc5, pb.h[1]);
                acc6 = __hadd2(acc6, pb.h[2]); acc7 = __hadd2(acc7, pb.h[3]);
            }
            const float mo = s_ms[j], m2o = s_m2s[j], Zo = s_zs[j];
            const int bo = s_bs[j];
            const bool takeOther = (mo > m) || (mo == m && bo < best);
            m2 = fmaxf(fmaxf(m2, m2o), fminf(m, mo));
            best = takeOther ? bo : best;
            m = fmaxf(m, mo);
            Z += Zo;
        }
        const float inv = 1.f / Z;
        if ((lane & 7) == 0) {
            const float2 f0 = __half22float2(acc0);
            const float2 f1 = __half22float2(acc1);
            const float2 f2 = __half22float2(acc2);
            const float2 f3 = __half22float2(acc3);
            const float2 f4 = __half22float2(acc4);
            const float2 f5 = __half22float2(acc5);
            const float2 f6 = __half22float2(acc6);
            const float2 f7 = __half22float2(acc7);
            s_sv[h * 4 + 0] = make_float4(f0.x * inv, f0.y * inv, f1.x * inv, f1.y * inv);
            s_sv[h * 4 + 1] = make_float4(f2.x * inv, f2.y * inv, f3.x * inv, f3.y * inv);
            s_sv[h * 4 + 2] = make_float4(f4.x * inv, f4.y * inv, f5.x * inv, f5.y * inv);
            s_sv[h * 4 + 3] = make_float4(f6.x * inv, f6.y * inv, f7.x * inv, f7.y * inv);
        }
        if (lane == 0) {
            out1[q] = (float)best;
            if (m - m2 < TAU) {
                const int ii = atomicAdd(cnt, 1);
                list[ii] = q;
            }
        }
        // same-wave DS ordering: s_sv writes visible to wave 0's reads below

        // epilogue: out[dp] = sum_c s[c]*Wout[c][dp] + bout[dp] + 2*query[q][dp]
        const int sub = lane & 31;
        const int half = lane >> 5;
        const int dpb = sub * 4;
        float4 r = {0.f, 0.f, 0.f, 0.f};
        if (half == 0) {
            const float4 b4 = *(const float4*)(bout + dpb);
            const float4 q4 = *(const float4*)(query + (size_t)q * EMBED + dpb);
            r.x = fmaf(2.f, q4.x, b4.x);
            r.y = fmaf(2.f, q4.y, b4.y);
            r.z = fmaf(2.f, q4.z, b4.z);
            r.w = fmaf(2.f, q4.w, b4.w);
        }
        const int cg0 = half * 16;
#pragma unroll 4
        for (int cg = cg0; cg < cg0 + 16; ++cg) {
            const float4 s4 = s_sv[cg];
            const float4 w0 = *(const float4*)(Wout + (size_t)(cg * 4 + 0) * EMBED + dpb);
            const float4 w1 = *(const float4*)(Wout + (size_t)(cg * 4 + 1) * EMBED + dpb);
            const float4 w2v = *(const float4*)(Wout + (size_t)(cg * 4 + 2) * EMBED + dpb);
            const float4 w3 = *(const float4*)(Wout + (size_t)(cg * 4 + 3) * EMBED + dpb);
            r.x = fmaf(s4.x, w0.x, r.x); r.y = fmaf(s4.x, w0.y, r.y);
            r.z = fmaf(s4.x, w0.z, r.z); r.w = fmaf(s4.x, w0.w, r.w);
            r.x = fmaf(s4.y, w1.x, r.x); r.y = fmaf(s4.y, w1.y, r.y);
            r.z = fmaf(s4.y, w1.z, r.z); r.w = fmaf(s4.y, w1.w, r.w);
            r.x = fmaf(s4.z, w2v.x, r.x); r.y = fmaf(s4.z, w2v.y, r.y);
            r.z = fmaf(s4.z, w2v.z, r.z); r.w = fmaf(s4.z, w2v.w, r.w);
            r.x = fmaf(s4.w, w3.x, r.x); r.y = fmaf(s4.w, w3.y, r.y);
            r.z = fmaf(s4.w, w3.z, r.z); r.w = fmaf(s4.w, w3.w, r.w);
        }
        {
            const float rx = __shfl_xor(r.x, 32, 64);
            const float ry = __shfl_xor(r.y, 32, 64);
            const float rz = __shfl_xor(r.z, 32, 64);
            const float rw = __shfl_xor(r.w, 32, 64);
            r.x += rx; r.y += ry; r.z += rz; r.w += rw;
        }
        if (half == 0)
            *(float4*)(out0 + (size_t)q * EMBED + dpb) = r;
    }
}

// ---------------------------------------------------------------------------
// Exact-f32 argmax fixup for flagged queries (bilinear of g == exact logit).
// ---------------------------------------------------------------------------
__global__ __launch_bounds__(64) void k_fix(
    const float* __restrict__ refp,
    const float* __restrict__ voff,
    const float* __restrict__ vaw,
    const float* __restrict__ gfield,  // (8, NPIX)
    const int* __restrict__ cnt,
    const int* __restrict__ list,
    float* __restrict__ out1) {
    const int n = *cnt;
    const int lane = threadIdx.x;
    for (int idx = blockIdx.x; idx < n; idx += gridDim.x) {
        const int q = list[idx];
        float logit = -1e30f;
        if (lane < NLVL) {
            const float rpx = refp[(size_t)q * 2];
            const float rpy = refp[((size_t)lane * NQ + q) * 2 + 1];
            float accl = 0.f;
            for (int h = 0; h < NHEADS; ++h) {
                const float4 o01 = *(const float4*)(voff + (size_t)q * 64 + h * 8);
                const float4 o23 = *(const float4*)(voff + (size_t)q * 64 + h * 8 + 4);
                const float4 aw4 = *(const float4*)(vaw + (size_t)q * 32 + h * 4);
                const float* gh = gfield + (size_t)h * NPIX;
                const float offx[4] = {o01.x, o01.z, o23.x, o23.z};
                const float offy[4] = {o01.y, o01.w, o23.y, o23.w};
                const float aww[4]  = {aw4.x, aw4.y, aw4.z, aw4.w};
#pragma unroll
                for (int p = 0; p < NPOINTS; ++p) {
                    const float px = fmaf(rpx, (float)WSP, offx[p]) - 0.5f;
                    const float py = fmaf(rpy, (float)HSP, offy[p]) - 0.5f;
                    const float fx = floorf(px), fy = floorf(py);
                    const float dx = px - fx, dy = py - fy;
                    const int x0 = (int)fx, y0 = (int)fy;
                    const float wx0 = ((unsigned)x0 < (unsigned)WSP) ? (1.f - dx) : 0.f;
                    const float wx1 = ((unsigned)(x0 + 1) < (unsigned)WSP) ? dx : 0.f;
                    const float t0 = ((unsigned)y0 < (unsigned)HSP) ? (1.f - dy) : 0.f;
                    const float t1 = ((unsigned)(y0 + 1) < (unsigned)HSP) ? dy : 0.f;
                    const int xc0 = min(max(x0, 0), WSP - 1);
                    const int xc1 = min(max(x0 + 1, 0), WSP - 1);
                    const int rb0 = min(max(y0, 0), HSP - 1) * WSP;
                    const int rb1 = min(max(y0 + 1, 0), HSP - 1) * WSP;
                    const float g00 = gh[rb0 + xc0];
                    const float g01 = gh[rb0 + xc1];
                    const float g10 = gh[rb1 + xc0];
                    const float g11 = gh[rb1 + xc1];
                    const float bil = wx0 * t0 * g00 + wx1 * t0 * g01
                                    + wx0 * t1 * g10 + wx1 * t1 * g11;
                    accl = fmaf(aww[p], bil, accl);
                }
            }
            logit = accl;
        }
        float v = logit;
        int b = lane;
#pragma unroll
        for (int d = 1; d < 64; d <<= 1) {
            const float vo = __shfl_xor(v, d, 64);
            const int bo = __shfl_xor(b, d, 64);
            if ((vo > v) || (vo == v && bo < b)) { v = vo; b = bo; }
        }
        if (lane == 0) out1[q] = (float)b;
    }
}

// ---------------------------------------------------------------------------
extern "C" void kernel_launch(void* const* d_in, const int* in_sizes, int n_in,
                              void* d_out, int out_size, void* d_ws, size_t ws_size,
                              hipStream_t stream) {
    const float* query = (const float*)d_in[0];
    const float* value = (const float*)d_in[1];
    const float* refp  = (const float*)d_in[2];
    const float* Woff  = (const float*)d_in[3];
    const float* boff  = (const float*)d_in[4];
    const float* Wattn = (const float*)d_in[5];
    const float* battn = (const float*)d_in[6];
    const float* Wval  = (const float*)d_in[7];
    const float* bval  = (const float*)d_in[8];
    const float* Wout  = (const float*)d_in[9];
    const float* bout  = (const float*)d_in[10];
    const float* Wproj = (const float*)d_in[11];
    // d_in[12] = b_proj: level-constant -> cancels in softmax/argmax, unused.

    float* ws = (float*)d_ws;
    __half* ws_vh = (__half*)ws;                          // 8*5202*16 halves
    float* ws_g   = ws + ((size_t)NHEADS * NPIX * HD + 1) / 2;  // 8*5202 f
    float* ws_off = ws_g + (size_t)NHEADS * NPIX;         // NQ*64
    float* ws_aw  = ws_off + (size_t)NQ * 64;             // NQ*32
    float* ws_u   = ws_aw + (size_t)NQ * 32;              // 128
    int*   ws_cnt = (int*)(ws_u + 128);                   // 1
    int*   ws_list = ws_cnt + 1;                          // NQ

    float* out0 = (float*)d_out;
    float* out1 = out0 + (size_t)NQ * EMBED;

    hipLaunchKernelGGL(k_uvec, dim3(1), dim3(128), 0, stream,
                       Wout, Wproj, ws_u, ws_cnt);
    hipLaunchKernelGGL(k_prep, dim3(NVB + NQB), dim3(256), 0, stream,
                       value, Wval, bval, query, Woff, boff, Wattn, battn,
                       ws_u, ws_vh, ws_g, ws_off, ws_aw);
    hipLaunchKernelGGL(k_main, dim3(NQ), dim3(256), 0, stream,
                       query, refp, ws_off, ws_aw, ws_vh, ws_u, Wout, bout,
                       out0, out1, ws_cnt, ws_list);
    hipLaunchKernelGGL(k_fix, dim3(256), dim3(64), 0, stream,
                       refp, ws_off, ws_aw, ws_g, ws_cnt, ws_list, out1);
}